// Round 7
// baseline (324.081 us; speedup 1.0000x reference)
//
#include <hip/hip_runtime.h>
#include <math.h>

#define Bb 32
#define Ss 2048
#define Hh 1024
#define QSq 1024
#define VSv 2048
#define SCH 32  // S-chunks in context partial

typedef float fx4 __attribute__((ext_vector_type(4)));

__device__ __forceinline__ float fast_tanh(float x) {
    // tanh(x) = 1 - 2/(e^{2x}+1); clamp so exp never overflows (tanh saturated anyway)
    float xc = fminf(fmaxf(x, -10.f), 10.f);
    float e  = __expf(2.f * xc);
    return 1.f - 2.f * __builtin_amdgcn_rcpf(e + 1.f);
}

__device__ __forceinline__ fx4 ntload4(const float* p) {
    return __builtin_nontemporal_load((const fx4*)p);
}
__device__ __forceinline__ void ntstore4(float* p, fx4 v) {
    __builtin_nontemporal_store(v, (fx4*)p);
}

// ---- K1: q[b,h] = sum_qs query[b,qs] * Wq[qs,h] ----------------------------
// grid = B*8 blocks of 128 threads; one thread per (b,h); full-chip coverage
__global__ void k_qproj(const float* __restrict__ query,
                        const float* __restrict__ Wq,
                        float* __restrict__ q) {
    __shared__ float qrow[QSq];
    const int b   = blockIdx.x >> 3;
    const int h0  = (blockIdx.x & 7) * 128;
    const int tid = threadIdx.x;
    for (int i = tid; i < QSq / 4; i += 128)
        ((float4*)qrow)[i] = ((const float4*)(query + b * QSq))[i];
    __syncthreads();
    const int h = h0 + tid;
    float a0 = 0.f, a1 = 0.f, a2 = 0.f, a3 = 0.f;
#pragma unroll 8
    for (int qs = 0; qs < QSq; qs += 4) {
        a0 += qrow[qs + 0] * Wq[(size_t)(qs + 0) * Hh + h];
        a1 += qrow[qs + 1] * Wq[(size_t)(qs + 1) * Hh + h];
        a2 += qrow[qs + 2] * Wq[(size_t)(qs + 2) * Hh + h];
        a3 += qrow[qs + 3] * Wq[(size_t)(qs + 3) * Hh + h];
    }
    q[b * Hh + h] = (a0 + a1) + (a2 + a3);
}

// ---- K2: scores[b,s] = sum_h v[h]*tanh(q[b,h]+pk[b,s,h]); -inf if masked ---
// grid = B*(S/8) blocks of 256 threads (4 waves, TWO s-rows per wave)
__device__ __forceinline__ float dot_tanh4(const float* sh_q, const float* sh_v,
                                           int h, fx4 p) {
    const float4 qv = *(const float4*)&sh_q[h];   // ds_read_b128, conflict-free
    const float4 vv = *(const float4*)&sh_v[h];
    float a;
    a  = vv.x * fast_tanh(qv.x + p.x);
    a += vv.y * fast_tanh(qv.y + p.y);
    a += vv.z * fast_tanh(qv.z + p.z);
    a += vv.w * fast_tanh(qv.w + p.w);
    return a;
}

__global__ void k_scores(const float* __restrict__ pk,
                         const int*   __restrict__ mask,
                         const float* __restrict__ q,
                         const float* __restrict__ ve,
                         float* __restrict__ scores) {
    __shared__ float sh_q[Hh];
    __shared__ float sh_v[Hh];
    const int tid = threadIdx.x;
    const int b   = blockIdx.x / (Ss / 8);
    const int s0  = (blockIdx.x % (Ss / 8)) * 8;
    ((float4*)sh_q)[tid] = ((const float4*)(q + b * Hh))[tid];
    ((float4*)sh_v)[tid] = ((const float4*)ve)[tid];
    __syncthreads();
    const int wave = tid >> 6, lane = tid & 63;
    const int s = s0 + wave * 2;
    const int m0 = mask[b * Ss + s], m1 = mask[b * Ss + s + 1];
    if (lane == 0) {
        if (!m0) scores[b * Ss + s]     = -INFINITY;
        if (!m1) scores[b * Ss + s + 1] = -INFINITY;
    }
    if (!m0 && !m1) return;
    const float* r0 = pk + (size_t)(b * Ss + s) * Hh;
    const float* r1 = r0 + Hh;
    float acc0 = 0.f, acc1 = 0.f;
    if (m0 && m1) {
        fx4 P0[4], P1[4];
#pragma unroll
        for (int j = 0; j < 4; ++j) P0[j] = ntload4(r0 + (j * 64 + lane) * 4);
#pragma unroll
        for (int j = 0; j < 4; ++j) P1[j] = ntload4(r1 + (j * 64 + lane) * 4);
#pragma unroll
        for (int j = 0; j < 4; ++j) {
            const int h = (j * 64 + lane) * 4;
            acc0 += dot_tanh4(sh_q, sh_v, h, P0[j]);
            acc1 += dot_tanh4(sh_q, sh_v, h, P1[j]);
        }
    } else {
        const float* r = m0 ? r0 : r1;
        fx4 P[4];
#pragma unroll
        for (int j = 0; j < 4; ++j) P[j] = ntload4(r + (j * 64 + lane) * 4);
        float acc = 0.f;
#pragma unroll
        for (int j = 0; j < 4; ++j) {
            const int h = (j * 64 + lane) * 4;
            acc += dot_tanh4(sh_q, sh_v, h, P[j]);
        }
        if (m0) acc0 = acc; else acc1 = acc;
    }
#pragma unroll
    for (int off = 32; off; off >>= 1) {
        acc0 += __shfl_xor(acc0, off);
        acc1 += __shfl_xor(acc1, off);
    }
    if (lane == 0) {
        if (m0) scores[b * Ss + s]     = acc0;
        if (m1) scores[b * Ss + s + 1] = acc1;
    }
}

// ---- K3: softmax over S per b; alphas into d_out + compacted live list -----
// grid = B blocks of 256 threads; thread t owns s in [t*8, t*8+8).
// Also zeroes the per-b ctx completion counter (runs before k_ctx in stream).
__global__ void k_softmax(const float* __restrict__ scores,
                          float* __restrict__ alphas,
                          int*   __restrict__ lidx,
                          float* __restrict__ lal,
                          int*   __restrict__ lcount,
                          int*   __restrict__ bcount) {
    const int b = blockIdx.x, tid = threadIdx.x;
    const int wave = tid >> 6, lane = tid & 63;
    if (tid == 0) bcount[b] = 0;
    __shared__ float sred[4];
    __shared__ float ssum[4];
    __shared__ int   swt[4];
    float v[8];
    *(float4*)&v[0] = *(const float4*)&scores[b * Ss + tid * 8];
    *(float4*)&v[4] = *(const float4*)&scores[b * Ss + tid * 8 + 4];
    float m = -INFINITY;
#pragma unroll
    for (int i = 0; i < 8; ++i) m = fmaxf(m, v[i]);
#pragma unroll
    for (int off = 32; off; off >>= 1) m = fmaxf(m, __shfl_xor(m, off));
    if (lane == 0) sred[wave] = m;
    __syncthreads();
    m = fmaxf(fmaxf(sred[0], sred[1]), fmaxf(sred[2], sred[3]));
    float e[8];
    float sum = 0.f;
#pragma unroll
    for (int i = 0; i < 8; ++i) { e[i] = __expf(v[i] - m); sum += e[i]; }
#pragma unroll
    for (int off = 32; off; off >>= 1) sum += __shfl_xor(sum, off);
    if (lane == 0) ssum[wave] = sum;
    __syncthreads();
    sum = (ssum[0] + ssum[1]) + (ssum[2] + ssum[3]);
    const float inv = 1.f / sum;
    float a[8];
#pragma unroll
    for (int i = 0; i < 8; ++i) a[i] = e[i] * inv;
    ntstore4(&alphas[b * Ss + tid * 8],     *(fx4*)&a[0]);
    ntstore4(&alphas[b * Ss + tid * 8 + 4], *(fx4*)&a[4]);

    // ---- compaction: sorted live indices + alphas (wave scan, 1 barrier) ---
    int c = 0;
#pragma unroll
    for (int i = 0; i < 8; ++i) c += (v[i] > -INFINITY) ? 1 : 0;
    int incl = c;
#pragma unroll
    for (int off = 1; off < 64; off <<= 1) {
        int y = __shfl_up(incl, off);
        if (lane >= off) incl += y;
    }
    if (lane == 63) swt[wave] = incl;
    __syncthreads();
    int base = 0;
#pragma unroll
    for (int w = 0; w < 4; ++w) base += (w < wave) ? swt[w] : 0;
    int pos = base + incl - c;
#pragma unroll
    for (int i = 0; i < 8; ++i) {
        if (v[i] > -INFINITY) {
            lidx[b * Ss + pos] = tid * 8 + i;
            lal[b * Ss + pos]  = a[i];
            ++pos;
        }
    }
    if (tid == 0) lcount[b] = swt[0] + swt[1] + swt[2] + swt[3];
}

// ---- K4: partial context sums + fused last-block fold ----------------------
// grid = B*SCH blocks of 256 threads; each thread owns cols c0 and c0+1024.
// 16 nt float4 loads in flight per wave. Last block per b (device-scope
// atomic counter) folds the SCH partials in fixed order -> deterministic.
__global__ void k_ctx_partial(const float* __restrict__ value,
                              const int*   __restrict__ lidx,
                              const float* __restrict__ lal,
                              const int*   __restrict__ lcount,
                              float* __restrict__ part,
                              int*   __restrict__ bcount,
                              float* __restrict__ ctx_out) {
    __shared__ int   sidx[64];
    __shared__ float sal[64];
    __shared__ int   sdone;
    const int tid = threadIdx.x;
    const int b   = blockIdx.x / SCH;
    const int sc  = blockIdx.x % SCH;
    const int c0  = tid * 4;
    const int count = lcount[b];
    const int chunk = (count + SCH - 1) / SCH;   // <= 64
    const int beg = sc * chunk;
    const int end = min(beg + chunk, count);
    const int n   = max(end - beg, 0);
    if (tid < n) {
        sidx[tid] = lidx[b * Ss + beg + tid];
        sal[tid]  = lal[b * Ss + beg + tid];
    }
    __syncthreads();
    const float* vb = value + (size_t)b * Ss * VSv;
    fx4 accA = {0.f, 0.f, 0.f, 0.f};
    fx4 accB = {0.f, 0.f, 0.f, 0.f};
    int i = 0;
    for (; i + 8 <= n; i += 8) {
        fx4   wa[8], wb[8];
        float a[8];
#pragma unroll
        for (int k = 0; k < 8; ++k) {
            const float* rp = vb + (size_t)sidx[i + k] * VSv + c0;
            wa[k] = ntload4(rp);
            wb[k] = ntload4(rp + 1024);
            a[k]  = sal[i + k];
        }
#pragma unroll
        for (int k = 0; k < 8; ++k) {
            accA += a[k] * wa[k];
            accB += a[k] * wb[k];
        }
    }
    for (; i < n; ++i) {
        const float a = sal[i];
        const float* rp = vb + (size_t)sidx[i] * VSv + c0;
        accA += a * ntload4(rp);
        accB += a * ntload4(rp + 1024);
    }
    float* pr = part + ((size_t)(b * SCH + sc)) * VSv + c0;
    *(fx4*)pr          = accA;
    *(fx4*)(pr + 1024) = accB;

    // ---- last block per b folds the partials (fixed order: deterministic) --
    __threadfence();                           // release partial writes
    if (tid == 0) sdone = atomicAdd(&bcount[b], 1);
    __syncthreads();
    if (sdone != SCH - 1) return;
    __threadfence();                           // acquire other blocks' writes
    fx4 fA = {0.f, 0.f, 0.f, 0.f};
    fx4 fB = {0.f, 0.f, 0.f, 0.f};
    const float* pb = part + (size_t)b * SCH * VSv + c0;
#pragma unroll 8
    for (int c = 0; c < SCH; ++c) {
        fA += ntload4(pb + (size_t)c * VSv);
        fB += ntload4(pb + (size_t)c * VSv + 1024);
    }
    float* outp = ctx_out + (size_t)b * VSv + c0;
    *(fx4*)outp          = fA;
    *(fx4*)(outp + 1024) = fB;
}

extern "C" void kernel_launch(void* const* d_in, const int* in_sizes, int n_in,
                              void* d_out, int out_size, void* d_ws, size_t ws_size,
                              hipStream_t stream) {
    const float* query    = (const float*)d_in[0];
    const float* proj_key = (const float*)d_in[1];
    const float* value    = (const float*)d_in[2];
    const int*   mask     = (const int*)d_in[3];
    const float* Wq       = (const float*)d_in[4];
    const float* v_energy = (const float*)d_in[5];

    float* out        = (float*)d_out;
    float* ctx_out    = out;                 // B*VS floats
    float* alphas_out = out + Bb * VSv;      // B*S floats

    float* ws     = (float*)d_ws;
    float* q      = ws;                       // B*H
    float* scores = q + Bb * Hh;              // B*S
    float* lal    = scores + Bb * Ss;         // B*S
    int*   lidx   = (int*)(lal + Bb * Ss);    // B*S
    int*   lcount = lidx + Bb * Ss;           // 32 ints
    int*   bcount = lcount + 32;              // 32 ints
    float* part   = (float*)(bcount + 32);    // B*SCH*VS = 8 MiB

    hipLaunchKernelGGL(k_qproj,       dim3(Bb * 8),         dim3(128), 0, stream, query, Wq, q);
    hipLaunchKernelGGL(k_scores,      dim3(Bb * (Ss / 8)),  dim3(256), 0, stream, proj_key, mask, q, v_energy, scores);
    hipLaunchKernelGGL(k_softmax,     dim3(Bb),             dim3(256), 0, stream, scores, alphas_out, lidx, lal, lcount, bcount);
    hipLaunchKernelGGL(k_ctx_partial, dim3(Bb * SCH),       dim3(256), 0, stream, value, lidx, lal, lcount, part, bcount, ctx_out);
}

// Round 8
// 97.593 us; speedup vs baseline: 3.3207x; 3.3207x over previous
//
#include <hip/hip_runtime.h>
#include <math.h>

#define Bb 32
#define Ss 2048
#define Hh 1024
#define QSq 1024
#define VSv 2048
#define SCH 32  // S-chunks in context partial

typedef float fx4 __attribute__((ext_vector_type(4)));

__device__ __forceinline__ float fast_tanh(float x) {
    // tanh(x) = 1 - 2/(e^{2x}+1); clamp so exp never overflows (tanh saturated anyway)
    float xc = fminf(fmaxf(x, -10.f), 10.f);
    float e  = __expf(2.f * xc);
    return 1.f - 2.f * __builtin_amdgcn_rcpf(e + 1.f);
}

__device__ __forceinline__ fx4 ntload4(const float* p) {
    return __builtin_nontemporal_load((const fx4*)p);
}
__device__ __forceinline__ void ntstore4(float* p, fx4 v) {
    __builtin_nontemporal_store(v, (fx4*)p);
}

// ---- K1: q[b,h] = sum_qs query[b,qs] * Wq[qs,h] ----------------------------
// grid = B*8 blocks of 128 threads; one thread per (b,h); full-chip coverage
__global__ void k_qproj(const float* __restrict__ query,
                        const float* __restrict__ Wq,
                        float* __restrict__ q) {
    __shared__ float qrow[QSq];
    const int b   = blockIdx.x >> 3;
    const int h0  = (blockIdx.x & 7) * 128;
    const int tid = threadIdx.x;
    for (int i = tid; i < QSq / 4; i += 128)
        ((float4*)qrow)[i] = ((const float4*)(query + b * QSq))[i];
    __syncthreads();
    const int h = h0 + tid;
    float a0 = 0.f, a1 = 0.f, a2 = 0.f, a3 = 0.f;
#pragma unroll 8
    for (int qs = 0; qs < QSq; qs += 4) {
        a0 += qrow[qs + 0] * Wq[(size_t)(qs + 0) * Hh + h];
        a1 += qrow[qs + 1] * Wq[(size_t)(qs + 1) * Hh + h];
        a2 += qrow[qs + 2] * Wq[(size_t)(qs + 2) * Hh + h];
        a3 += qrow[qs + 3] * Wq[(size_t)(qs + 3) * Hh + h];
    }
    q[b * Hh + h] = (a0 + a1) + (a2 + a3);
}

// ---- K2: scores[b,s] = sum_h v[h]*tanh(q[b,h]+pk[b,s,h]); -inf if masked ---
// grid = B*(S/8) blocks of 256 threads (4 waves, TWO s-rows per wave)
__device__ __forceinline__ float dot_tanh4(const float* sh_q, const float* sh_v,
                                           int h, fx4 p) {
    const float4 qv = *(const float4*)&sh_q[h];   // ds_read_b128, conflict-free
    const float4 vv = *(const float4*)&sh_v[h];
    float a;
    a  = vv.x * fast_tanh(qv.x + p.x);
    a += vv.y * fast_tanh(qv.y + p.y);
    a += vv.z * fast_tanh(qv.z + p.z);
    a += vv.w * fast_tanh(qv.w + p.w);
    return a;
}

__global__ void k_scores(const float* __restrict__ pk,
                         const int*   __restrict__ mask,
                         const float* __restrict__ q,
                         const float* __restrict__ ve,
                         float* __restrict__ scores) {
    __shared__ float sh_q[Hh];
    __shared__ float sh_v[Hh];
    const int tid = threadIdx.x;
    const int b   = blockIdx.x / (Ss / 8);
    const int s0  = (blockIdx.x % (Ss / 8)) * 8;
    ((float4*)sh_q)[tid] = ((const float4*)(q + b * Hh))[tid];
    ((float4*)sh_v)[tid] = ((const float4*)ve)[tid];
    __syncthreads();
    const int wave = tid >> 6, lane = tid & 63;
    const int s = s0 + wave * 2;
    const int m0 = mask[b * Ss + s], m1 = mask[b * Ss + s + 1];
    if (lane == 0) {
        if (!m0) scores[b * Ss + s]     = -INFINITY;
        if (!m1) scores[b * Ss + s + 1] = -INFINITY;
    }
    if (!m0 && !m1) return;
    const float* r0 = pk + (size_t)(b * Ss + s) * Hh;
    const float* r1 = r0 + Hh;
    float acc0 = 0.f, acc1 = 0.f;
    if (m0 && m1) {
        fx4 P0[4], P1[4];
#pragma unroll
        for (int j = 0; j < 4; ++j) P0[j] = ntload4(r0 + (j * 64 + lane) * 4);
#pragma unroll
        for (int j = 0; j < 4; ++j) P1[j] = ntload4(r1 + (j * 64 + lane) * 4);
#pragma unroll
        for (int j = 0; j < 4; ++j) {
            const int h = (j * 64 + lane) * 4;
            acc0 += dot_tanh4(sh_q, sh_v, h, P0[j]);
            acc1 += dot_tanh4(sh_q, sh_v, h, P1[j]);
        }
    } else {
        const float* r = m0 ? r0 : r1;
        fx4 P[4];
#pragma unroll
        for (int j = 0; j < 4; ++j) P[j] = ntload4(r + (j * 64 + lane) * 4);
        float acc = 0.f;
#pragma unroll
        for (int j = 0; j < 4; ++j) {
            const int h = (j * 64 + lane) * 4;
            acc += dot_tanh4(sh_q, sh_v, h, P[j]);
        }
        if (m0) acc0 = acc; else acc1 = acc;
    }
#pragma unroll
    for (int off = 32; off; off >>= 1) {
        acc0 += __shfl_xor(acc0, off);
        acc1 += __shfl_xor(acc1, off);
    }
    if (lane == 0) {
        if (m0) scores[b * Ss + s]     = acc0;
        if (m1) scores[b * Ss + s + 1] = acc1;
    }
}

// ---- K3: softmax over S per b; alphas into d_out + compacted live list -----
// grid = B blocks of 256 threads; thread t owns s in [t*8, t*8+8)
__global__ void k_softmax(const float* __restrict__ scores,
                          float* __restrict__ alphas,
                          int*   __restrict__ lidx,
                          float* __restrict__ lal,
                          int*   __restrict__ lcount) {
    const int b = blockIdx.x, tid = threadIdx.x;
    const int wave = tid >> 6, lane = tid & 63;
    __shared__ float sred[4];
    __shared__ float ssum[4];
    __shared__ int   swt[4];
    float v[8];
    *(float4*)&v[0] = *(const float4*)&scores[b * Ss + tid * 8];
    *(float4*)&v[4] = *(const float4*)&scores[b * Ss + tid * 8 + 4];
    float m = -INFINITY;
#pragma unroll
    for (int i = 0; i < 8; ++i) m = fmaxf(m, v[i]);
#pragma unroll
    for (int off = 32; off; off >>= 1) m = fmaxf(m, __shfl_xor(m, off));
    if (lane == 0) sred[wave] = m;
    __syncthreads();
    m = fmaxf(fmaxf(sred[0], sred[1]), fmaxf(sred[2], sred[3]));
    float e[8];
    float sum = 0.f;
#pragma unroll
    for (int i = 0; i < 8; ++i) { e[i] = __expf(v[i] - m); sum += e[i]; }
#pragma unroll
    for (int off = 32; off; off >>= 1) sum += __shfl_xor(sum, off);
    if (lane == 0) ssum[wave] = sum;
    __syncthreads();
    sum = (ssum[0] + ssum[1]) + (ssum[2] + ssum[3]);
    const float inv = 1.f / sum;
    float a[8];
#pragma unroll
    for (int i = 0; i < 8; ++i) a[i] = e[i] * inv;
    ntstore4(&alphas[b * Ss + tid * 8],     *(fx4*)&a[0]);
    ntstore4(&alphas[b * Ss + tid * 8 + 4], *(fx4*)&a[4]);

    // ---- compaction: sorted live indices + alphas (wave scan, 1 barrier) ---
    int c = 0;
#pragma unroll
    for (int i = 0; i < 8; ++i) c += (v[i] > -INFINITY) ? 1 : 0;
    int incl = c;
#pragma unroll
    for (int off = 1; off < 64; off <<= 1) {
        int y = __shfl_up(incl, off);
        if (lane >= off) incl += y;
    }
    if (lane == 63) swt[wave] = incl;
    __syncthreads();
    int base = 0;
#pragma unroll
    for (int w = 0; w < 4; ++w) base += (w < wave) ? swt[w] : 0;
    int pos = base + incl - c;
#pragma unroll
    for (int i = 0; i < 8; ++i) {
        if (v[i] > -INFINITY) {
            lidx[b * Ss + pos] = tid * 8 + i;
            lal[b * Ss + pos]  = a[i];
            ++pos;
        }
    }
    if (tid == 0) lcount[b] = swt[0] + swt[1] + swt[2] + swt[3];
}

// ---- K4: partial context sums over chunks of the LIVE list -----------------
// grid = B*SCH blocks of 256 threads; each thread owns cols c0 and c0+1024.
// 8 rows x 2 halves = 16 nt float4 loads in flight per wave.
__global__ void k_ctx_partial(const float* __restrict__ value,
                              const int*   __restrict__ lidx,
                              const float* __restrict__ lal,
                              const int*   __restrict__ lcount,
                              float* __restrict__ part) {
    __shared__ int   sidx[64];
    __shared__ float sal[64];
    const int tid = threadIdx.x;
    const int b   = blockIdx.x / SCH;
    const int sc  = blockIdx.x % SCH;
    const int c0  = tid * 4;
    const int count = lcount[b];
    const int chunk = (count + SCH - 1) / SCH;   // <= 64
    const int beg = sc * chunk;
    const int end = min(beg + chunk, count);
    const int n   = max(end - beg, 0);
    if (tid < n) {
        sidx[tid] = lidx[b * Ss + beg + tid];
        sal[tid]  = lal[b * Ss + beg + tid];
    }
    __syncthreads();
    const float* vb = value + (size_t)b * Ss * VSv;
    fx4 accA = {0.f, 0.f, 0.f, 0.f};
    fx4 accB = {0.f, 0.f, 0.f, 0.f};
    int i = 0;
    for (; i + 8 <= n; i += 8) {
        fx4   wa[8], wb[8];
        float a[8];
#pragma unroll
        for (int k = 0; k < 8; ++k) {
            const float* rp = vb + (size_t)sidx[i + k] * VSv + c0;
            wa[k] = ntload4(rp);
            wb[k] = ntload4(rp + 1024);
            a[k]  = sal[i + k];
        }
#pragma unroll
        for (int k = 0; k < 8; ++k) {
            accA += a[k] * wa[k];
            accB += a[k] * wb[k];
        }
    }
    for (; i < n; ++i) {
        const float a = sal[i];
        const float* rp = vb + (size_t)sidx[i] * VSv + c0;
        accA += a * ntload4(rp);
        accB += a * ntload4(rp + 1024);
    }
    float* pr = part + ((size_t)(b * SCH + sc)) * VSv + c0;
    *(fx4*)pr          = accA;
    *(fx4*)(pr + 1024) = accB;
}

// ---- K5: fold SCH partials into context (float4, 1-wave blocks, 256 CUs) ---
__global__ void k_ctx_reduce(const float* __restrict__ part,
                             float* __restrict__ out) {
    const int idx = blockIdx.x * 64 + threadIdx.x;    // over B*VS/4
    const int b = idx / (VSv / 4), v4 = idx % (VSv / 4);
    fx4 acc = {0.f, 0.f, 0.f, 0.f};
#pragma unroll 8
    for (int c = 0; c < SCH; ++c) {
        acc += ntload4(part + ((size_t)(b * SCH + c)) * VSv + v4 * 4);
    }
    *(fx4*)(out + (size_t)b * VSv + v4 * 4) = acc;
}

extern "C" void kernel_launch(void* const* d_in, const int* in_sizes, int n_in,
                              void* d_out, int out_size, void* d_ws, size_t ws_size,
                              hipStream_t stream) {
    const float* query    = (const float*)d_in[0];
    const float* proj_key = (const float*)d_in[1];
    const float* value    = (const float*)d_in[2];
    const int*   mask     = (const int*)d_in[3];
    const float* Wq       = (const float*)d_in[4];
    const float* v_energy = (const float*)d_in[5];

    float* out        = (float*)d_out;
    float* ctx_out    = out;                 // B*VS floats
    float* alphas_out = out + Bb * VSv;      // B*S floats

    float* ws     = (float*)d_ws;
    float* q      = ws;                       // B*H
    float* scores = q + Bb * Hh;              // B*S
    float* lal    = scores + Bb * Ss;         // B*S
    int*   lidx   = (int*)(lal + Bb * Ss);    // B*S
    int*   lcount = lidx + Bb * Ss;           // 32 ints
    float* part   = (float*)(lcount + 32);    // B*SCH*VS = 8 MiB

    hipLaunchKernelGGL(k_qproj,       dim3(Bb * 8),            dim3(128), 0, stream, query, Wq, q);
    hipLaunchKernelGGL(k_scores,      dim3(Bb * (Ss / 8)),     dim3(256), 0, stream, proj_key, mask, q, v_energy, scores);
    hipLaunchKernelGGL(k_softmax,     dim3(Bb),                dim3(256), 0, stream, scores, alphas_out, lidx, lal, lcount);
    hipLaunchKernelGGL(k_ctx_partial, dim3(Bb * SCH),          dim3(256), 0, stream, value, lidx, lal, lcount, part);
    hipLaunchKernelGGL(k_ctx_reduce,  dim3(Bb * VSv / 4 / 64), dim3(64),  0, stream, part, ctx_out);
}

// Round 9
// 94.612 us; speedup vs baseline: 3.4254x; 1.0315x over previous
//
#include <hip/hip_runtime.h>
#include <math.h>

#define Bb 32
#define Ss 2048
#define Hh 1024
#define QSq 1024
#define VSv 2048
#define SCH 32  // S-chunks in context partial

typedef float fx4 __attribute__((ext_vector_type(4)));

__device__ __forceinline__ float fast_tanh(float x) {
    // tanh(x) = 1 - 2/(e^{2x}+1). No clamp needed: exp overflow -> inf -> rcp -> 0 -> 1;
    // underflow -> 0 -> 1 - 2/1 = -1. v_exp_f32 is exp2, so scale by 2*log2(e).
    float e = __builtin_amdgcn_exp2f(x * 2.8853900817779268f);
    return 1.f - 2.f * __builtin_amdgcn_rcpf(e + 1.f);
}

__device__ __forceinline__ fx4 ntload4(const float* p) {
    return __builtin_nontemporal_load((const fx4*)p);
}
__device__ __forceinline__ void ntstore4(float* p, fx4 v) {
    __builtin_nontemporal_store(v, (fx4*)p);
}

// ---- K1: q[b,h] = sum_qs query[b,qs] * Wq[qs,h] ----------------------------
// grid = B*8 blocks of 128 threads; one thread per (b,h); full-chip coverage
__global__ void k_qproj(const float* __restrict__ query,
                        const float* __restrict__ Wq,
                        float* __restrict__ q) {
    __shared__ float qrow[QSq];
    const int b   = blockIdx.x >> 3;
    const int h0  = (blockIdx.x & 7) * 128;
    const int tid = threadIdx.x;
    for (int i = tid; i < QSq / 4; i += 128)
        ((float4*)qrow)[i] = ((const float4*)(query + b * QSq))[i];
    __syncthreads();
    const int h = h0 + tid;
    float a0 = 0.f, a1 = 0.f, a2 = 0.f, a3 = 0.f;
#pragma unroll 8
    for (int qs = 0; qs < QSq; qs += 4) {
        a0 += qrow[qs + 0] * Wq[(size_t)(qs + 0) * Hh + h];
        a1 += qrow[qs + 1] * Wq[(size_t)(qs + 1) * Hh + h];
        a2 += qrow[qs + 2] * Wq[(size_t)(qs + 2) * Hh + h];
        a3 += qrow[qs + 3] * Wq[(size_t)(qs + 3) * Hh + h];
    }
    q[b * Hh + h] = (a0 + a1) + (a2 + a3);
}

// ---- K2: scores[b,s] = sum_h v[h]*tanh(q[b,h]+pk[b,s,h]); -inf if masked ---
// grid = B*(S/8) blocks of 256 threads (4 waves, TWO s-rows per wave)
__device__ __forceinline__ float dot_tanh4(const float* sh_q, const float* sh_v,
                                           int h, fx4 p) {
    const float4 qv = *(const float4*)&sh_q[h];   // ds_read_b128
    const float4 vv = *(const float4*)&sh_v[h];
    float a;
    a  = vv.x * fast_tanh(qv.x + p.x);
    a += vv.y * fast_tanh(qv.y + p.y);
    a += vv.z * fast_tanh(qv.z + p.z);
    a += vv.w * fast_tanh(qv.w + p.w);
    return a;
}

__global__ void k_scores(const float* __restrict__ pk,
                         const int*   __restrict__ mask,
                         const float* __restrict__ q,
                         const float* __restrict__ ve,
                         float* __restrict__ scores) {
    __shared__ float sh_q[Hh];
    __shared__ float sh_v[Hh];
    const int tid = threadIdx.x;
    const int b   = blockIdx.x / (Ss / 8);
    const int s0  = (blockIdx.x % (Ss / 8)) * 8;
    ((float4*)sh_q)[tid] = ((const float4*)(q + b * Hh))[tid];
    ((float4*)sh_v)[tid] = ((const float4*)ve)[tid];
    __syncthreads();
    const int wave = tid >> 6, lane = tid & 63;
    const int s = s0 + wave * 2;
    const int m0 = mask[b * Ss + s], m1 = mask[b * Ss + s + 1];
    if (lane == 0) {
        if (!m0) scores[b * Ss + s]     = -INFINITY;
        if (!m1) scores[b * Ss + s + 1] = -INFINITY;
    }
    if (!m0 && !m1) return;
    const float* r0 = pk + (size_t)(b * Ss + s) * Hh;
    const float* r1 = r0 + Hh;
    float acc0 = 0.f, acc1 = 0.f;
    if (m0 && m1) {
        fx4 P0[4], P1[4];
#pragma unroll
        for (int j = 0; j < 4; ++j) P0[j] = ntload4(r0 + (j * 64 + lane) * 4);
#pragma unroll
        for (int j = 0; j < 4; ++j) P1[j] = ntload4(r1 + (j * 64 + lane) * 4);
#pragma unroll
        for (int j = 0; j < 4; ++j) {
            const int h = (j * 64 + lane) * 4;
            acc0 += dot_tanh4(sh_q, sh_v, h, P0[j]);
            acc1 += dot_tanh4(sh_q, sh_v, h, P1[j]);
        }
    } else {
        const float* r = m0 ? r0 : r1;
        fx4 P[4];
#pragma unroll
        for (int j = 0; j < 4; ++j) P[j] = ntload4(r + (j * 64 + lane) * 4);
        float acc = 0.f;
#pragma unroll
        for (int j = 0; j < 4; ++j) {
            const int h = (j * 64 + lane) * 4;
            acc += dot_tanh4(sh_q, sh_v, h, P[j]);
        }
        if (m0) acc0 = acc; else acc1 = acc;
    }
#pragma unroll
    for (int off = 32; off; off >>= 1) {
        acc0 += __shfl_xor(acc0, off);
        acc1 += __shfl_xor(acc1, off);
    }
    if (lane == 0) {
        if (m0) scores[b * Ss + s]     = acc0;
        if (m1) scores[b * Ss + s + 1] = acc1;
    }
}

// ---- K3: softmax over S per b; alphas into d_out + compacted live list -----
// grid = B blocks of 256 threads; thread t owns s in [t*8, t*8+8)
__global__ void k_softmax(const float* __restrict__ scores,
                          float* __restrict__ alphas,
                          int*   __restrict__ lidx,
                          float* __restrict__ lal,
                          int*   __restrict__ lcount) {
    const int b = blockIdx.x, tid = threadIdx.x;
    const int wave = tid >> 6, lane = tid & 63;
    __shared__ float sred[4];
    __shared__ float ssum[4];
    __shared__ int   swt[4];
    float v[8];
    *(float4*)&v[0] = *(const float4*)&scores[b * Ss + tid * 8];
    *(float4*)&v[4] = *(const float4*)&scores[b * Ss + tid * 8 + 4];
    float m = -INFINITY;
#pragma unroll
    for (int i = 0; i < 8; ++i) m = fmaxf(m, v[i]);
#pragma unroll
    for (int off = 32; off; off >>= 1) m = fmaxf(m, __shfl_xor(m, off));
    if (lane == 0) sred[wave] = m;
    __syncthreads();
    m = fmaxf(fmaxf(sred[0], sred[1]), fmaxf(sred[2], sred[3]));
    float e[8];
    float sum = 0.f;
#pragma unroll
    for (int i = 0; i < 8; ++i) { e[i] = __expf(v[i] - m); sum += e[i]; }
#pragma unroll
    for (int off = 32; off; off >>= 1) sum += __shfl_xor(sum, off);
    if (lane == 0) ssum[wave] = sum;
    __syncthreads();
    sum = (ssum[0] + ssum[1]) + (ssum[2] + ssum[3]);
    const float inv = 1.f / sum;
    float a[8];
#pragma unroll
    for (int i = 0; i < 8; ++i) a[i] = e[i] * inv;
    ntstore4(&alphas[b * Ss + tid * 8],     *(fx4*)&a[0]);
    ntstore4(&alphas[b * Ss + tid * 8 + 4], *(fx4*)&a[4]);

    // ---- compaction: sorted live indices + alphas (wave scan, 1 barrier) ---
    int c = 0;
#pragma unroll
    for (int i = 0; i < 8; ++i) c += (v[i] > -INFINITY) ? 1 : 0;
    int incl = c;
#pragma unroll
    for (int off = 1; off < 64; off <<= 1) {
        int y = __shfl_up(incl, off);
        if (lane >= off) incl += y;
    }
    if (lane == 63) swt[wave] = incl;
    __syncthreads();
    int base = 0;
#pragma unroll
    for (int w = 0; w < 4; ++w) base += (w < wave) ? swt[w] : 0;
    int pos = base + incl - c;
#pragma unroll
    for (int i = 0; i < 8; ++i) {
        if (v[i] > -INFINITY) {
            lidx[b * Ss + pos] = tid * 8 + i;
            lal[b * Ss + pos]  = a[i];
            ++pos;
        }
    }
    if (tid == 0) lcount[b] = swt[0] + swt[1] + swt[2] + swt[3];
}

// ---- K4: partial context sums over chunks of the LIVE list -----------------
// grid = B*SCH blocks of 256 threads; each thread owns cols c0 and c0+1024.
// 8 rows x 2 halves = 16 nt float4 loads in flight; 8-wide, 4-wide, <=3 tail.
__global__ void k_ctx_partial(const float* __restrict__ value,
                              const int*   __restrict__ lidx,
                              const float* __restrict__ lal,
                              const int*   __restrict__ lcount,
                              float* __restrict__ part) {
    __shared__ int   sidx[64];
    __shared__ float sal[64];
    const int tid = threadIdx.x;
    const int b   = blockIdx.x / SCH;
    const int sc  = blockIdx.x % SCH;
    const int c0  = tid * 4;
    const int count = lcount[b];
    const int chunk = (count + SCH - 1) / SCH;   // <= 64
    const int beg = sc * chunk;
    const int end = min(beg + chunk, count);
    const int n   = max(end - beg, 0);
    if (tid < n) {
        sidx[tid] = lidx[b * Ss + beg + tid];
        sal[tid]  = lal[b * Ss + beg + tid];
    }
    __syncthreads();
    const float* vb = value + (size_t)b * Ss * VSv;
    fx4 accA = {0.f, 0.f, 0.f, 0.f};
    fx4 accB = {0.f, 0.f, 0.f, 0.f};
    int i = 0;
    for (; i + 8 <= n; i += 8) {
        fx4   wa[8], wb[8];
        float a[8];
#pragma unroll
        for (int k = 0; k < 8; ++k) {
            const float* rp = vb + (size_t)sidx[i + k] * VSv + c0;
            wa[k] = ntload4(rp);
            wb[k] = ntload4(rp + 1024);
            a[k]  = sal[i + k];
        }
#pragma unroll
        for (int k = 0; k < 8; ++k) {
            accA += a[k] * wa[k];
            accB += a[k] * wb[k];
        }
    }
    if (i + 4 <= n) {
        fx4   wa[4], wb[4];
        float a[4];
#pragma unroll
        for (int k = 0; k < 4; ++k) {
            const float* rp = vb + (size_t)sidx[i + k] * VSv + c0;
            wa[k] = ntload4(rp);
            wb[k] = ntload4(rp + 1024);
            a[k]  = sal[i + k];
        }
#pragma unroll
        for (int k = 0; k < 4; ++k) {
            accA += a[k] * wa[k];
            accB += a[k] * wb[k];
        }
        i += 4;
    }
    for (; i < n; ++i) {
        const float a = sal[i];
        const float* rp = vb + (size_t)sidx[i] * VSv + c0;
        accA += a * ntload4(rp);
        accB += a * ntload4(rp + 1024);
    }
    float* pr = part + ((size_t)(b * SCH + sc)) * VSv + c0;
    *(fx4*)pr          = accA;
    *(fx4*)(pr + 1024) = accB;
}

// ---- K5: fold SCH partials into context (float4, 1-wave blocks, 256 CUs) ---
__global__ void k_ctx_reduce(const float* __restrict__ part,
                             float* __restrict__ out) {
    const int idx = blockIdx.x * 64 + threadIdx.x;    // over B*VS/4
    const int b = idx / (VSv / 4), v4 = idx % (VSv / 4);
    fx4 acc = {0.f, 0.f, 0.f, 0.f};
#pragma unroll 8
    for (int c = 0; c < SCH; ++c) {
        acc += ntload4(part + ((size_t)(b * SCH + c)) * VSv + v4 * 4);
    }
    *(fx4*)(out + (size_t)b * VSv + v4 * 4) = acc;
}

extern "C" void kernel_launch(void* const* d_in, const int* in_sizes, int n_in,
                              void* d_out, int out_size, void* d_ws, size_t ws_size,
                              hipStream_t stream) {
    const float* query    = (const float*)d_in[0];
    const float* proj_key = (const float*)d_in[1];
    const float* value    = (const float*)d_in[2];
    const int*   mask     = (const int*)d_in[3];
    const float* Wq       = (const float*)d_in[4];
    const float* v_energy = (const float*)d_in[5];

    float* out        = (float*)d_out;
    float* ctx_out    = out;                 // B*VS floats
    float* alphas_out = out + Bb * VSv;      // B*S floats

    float* ws     = (float*)d_ws;
    float* q      = ws;                       // B*H
    float* scores = q + Bb * Hh;              // B*S
    float* lal    = scores + Bb * Ss;         // B*S
    int*   lidx   = (int*)(lal + Bb * Ss);    // B*S
    int*   lcount = lidx + Bb * Ss;           // 32 ints
    float* part   = (float*)(lcount + 32);    // B*SCH*VS = 8 MiB

    hipLaunchKernelGGL(k_qproj,       dim3(Bb * 8),            dim3(128), 0, stream, query, Wq, q);
    hipLaunchKernelGGL(k_scores,      dim3(Bb * (Ss / 8)),     dim3(256), 0, stream, proj_key, mask, q, v_energy, scores);
    hipLaunchKernelGGL(k_softmax,     dim3(Bb),                dim3(256), 0, stream, scores, alphas_out, lidx, lal, lcount);
    hipLaunchKernelGGL(k_ctx_partial, dim3(Bb * SCH),          dim3(256), 0, stream, value, lidx, lal, lcount, part);
    hipLaunchKernelGGL(k_ctx_reduce,  dim3(Bb * VSv / 4 / 64), dim3(64),  0, stream, part, ctx_out);
}